// Round 10
// baseline (398.755 us; speedup 1.0000x reference)
//
#include <hip/hip_runtime.h>

typedef __bf16 bf16x8 __attribute__((ext_vector_type(8)));
typedef float f32x4 __attribute__((ext_vector_type(4)));

#define B_ 2
#define T_ 2048
#define D_ 1024
#define H_ 16

__device__ __forceinline__ ushort f2bf(float f) {
  union { float f; unsigned u; } v; v.f = f;
  unsigned u = v.u;
  return (ushort)((u + 0x7FFFu + ((u >> 16) & 1u)) >> 16);
}

// async global->LDS, 16B per lane; LDS dest is wave-uniform base + lane*16
__device__ __forceinline__ void g2l16(const void* g, void* l) {
  __builtin_amdgcn_global_load_lds(
      (const __attribute__((address_space(1))) unsigned int*)g,
      (__attribute__((address_space(3))) unsigned int*)l, 16, 0, 0);
}

// ---------------- cast x -> bf16 ----------------
__global__ __launch_bounds__(256) void cvt_kernel(const float* __restrict__ in,
                                                  ushort* __restrict__ out) {
  int i = (blockIdx.x * 256 + threadIdx.x) * 4;
  float4 v = *(const float4*)(in + i);
  ushort4 o;
  o.x = f2bf(v.x); o.y = f2bf(v.y); o.z = f2bf(v.z); o.w = f2bf(v.w);
  *(ushort4*)(out + i) = o;
}

// ---------------- transpose + cast: in[R][C] f32 -> out[C][R] bf16 ----------------
__global__ void transpose_cvt(const float* __restrict__ in, ushort* __restrict__ out,
                              int R, int C) {
  __shared__ float tile[32][33];
  int bx = blockIdx.x * 32, by = blockIdx.y * 32;
  int tx = threadIdx.x, ty = threadIdx.y;  // block (32,8)
  for (int i = 0; i < 32; i += 8)
    tile[ty + i][tx] = in[(size_t)(by + ty + i) * C + (bx + tx)];
  __syncthreads();
  for (int i = 0; i < 32; i += 8)
    out[(size_t)(bx + ty + i) * R + (by + tx)] = f2bf(tile[tx][ty + i]);
}

// ---------------- bf16 GEMM (m97-style): C[M,N] = A[M,K] * BT[N,K]^T (+bias) ----------------
__global__ __launch_bounds__(256) void gemm_bf16(
    const ushort* __restrict__ A, const ushort* __restrict__ BT,
    float* __restrict__ C, const float* __restrict__ bias,
    int M, int N, int K) {
  __shared__ alignas(16) ushort As[2][4096];  // 128 rows x 32 cols
  __shared__ alignas(16) ushort Bs[2][4096];
  int tid = threadIdx.x;
  int wave = tid >> 6, lane = tid & 63;
  int l16 = lane & 15, lhi = lane >> 4;
  int m0 = blockIdx.y * 128, n0 = blockIdx.x * 128;
  int wr = (wave >> 1) * 64, wc = (wave & 1) * 64;
  int srow = lane >> 2, sch = lane & 3;  // staging: 4 lanes per 64B row

  f32x4 acc[4][4] = {};

  auto stage = [&](int kk, int buf) {
    for (int i = 0; i < 2; ++i) {
      int rg = i * 4 + wave;  // 0..7, 16 rows each
      const ushort* ga = A + (size_t)(m0 + rg * 16 + srow) * K + kk + sch * 8;
      const ushort* gb = BT + (size_t)(n0 + rg * 16 + srow) * K + kk + sch * 8;
      g2l16(ga, &As[buf][rg * 512]);
      g2l16(gb, &Bs[buf][rg * 512]);
    }
  };

  stage(0, 0);
  int buf = 0;
  for (int kk = 0; kk < K; kk += 32) {
    __syncthreads();
    if (kk + 32 < K) stage(kk + 32, buf ^ 1);
    const ushort* Asb = As[buf];
    const ushort* Bsb = Bs[buf];
    bf16x8 af[4], bfr[4];
    for (int f = 0; f < 4; ++f)
      af[f] = *(const bf16x8*)(Asb + (wr + f * 16 + l16) * 32 + lhi * 8);
    for (int f = 0; f < 4; ++f)
      bfr[f] = *(const bf16x8*)(Bsb + (wc + f * 16 + l16) * 32 + lhi * 8);
    for (int fm = 0; fm < 4; ++fm)
      for (int fn = 0; fn < 4; ++fn)
        acc[fm][fn] = __builtin_amdgcn_mfma_f32_16x16x32_bf16(af[fm], bfr[fn], acc[fm][fn], 0, 0, 0);
    buf ^= 1;
  }
  for (int fm = 0; fm < 4; ++fm)
    for (int fn = 0; fn < 4; ++fn)
      for (int r = 0; r < 4; ++r) {
        int row = m0 + wr + fm * 16 + lhi * 4 + r;
        int col = n0 + wc + fn * 16 + l16;
        float v = acc[fm][fn][r];
        if (bias) v += bias[col];
        C[(size_t)row * N + col] = v;
      }
}

// ---------------- build Qaug/Kaug/V from qkv ----------------
__global__ __launch_bounds__(256) void augment_kernel(
    const float* __restrict__ qkv,  // [B*T, 3072]
    ushort* __restrict__ Qaug, ushort* __restrict__ Kaug, ushort* __restrict__ Vb) {
  int row = blockIdx.x;  // b*T + t
  int b = row >> 11;
  int t = row & 2047;
  int tid = threadIdx.x;
  const float* src = qkv + (size_t)row * 3072;
  for (int i = 0; i < 4; ++i) {
    int idx = tid + i * 256;  // 0..1023
    int h = idx >> 6, d = idx & 63;
    size_t obase = ((size_t)(b * H_ + h) * T_ + t);
    float q = src[idx];
    float k = src[1024 + idx];
    float v = src[2048 + idx];
    Qaug[obase * 128 + d] = f2bf(q * 0.125f);
    Kaug[obase * 128 + d] = f2bf(k);
    Vb[obase * 64 + d] = f2bf(v);
  }
  for (int i = 0; i < 2; ++i) {
    int idx = tid + i * 256;  // 0..511
    int h = idx >> 5, mm = idx & 31;
    int gdim = h * 64 + 2 * mm;
    float w = __expf(-9.2103403719761836f * (float)gdim * (1.0f / 1024.0f));
    float ang = w * (float)t;
    float si, co;
    __sincosf(ang, &si, &co);
    float qs = src[h * 64 + 2 * mm], qc = src[h * 64 + 2 * mm + 1];
    size_t obase = ((size_t)(b * H_ + h) * T_ + t);
    Qaug[obase * 128 + 64 + 2 * mm]     = f2bf((qs * si + qc * co) * 0.125f);
    Qaug[obase * 128 + 64 + 2 * mm + 1] = f2bf((qc * si - qs * co) * 0.125f);
    Kaug[obase * 128 + 64 + 2 * mm]     = f2bf(co);
    Kaug[obase * 128 + 64 + 2 * mm + 1] = f2bf(si);
  }
}

// ---------------- transpose V: [BH, T, 64] -> [BH, 64, T] ----------------
__global__ __launch_bounds__(256) void transpose_v(const ushort* __restrict__ Vb,
                                                   ushort* __restrict__ Vt) {
  __shared__ ushort tile[64][72];
  int bh = blockIdx.y, t0 = blockIdx.x * 64;
  int tid = threadIdx.x;
  for (int i = 0; i < 2; ++i) {
    int e = tid + i * 256;           // 0..511
    int row = e >> 3, ch = e & 7;    // t-row, 8 dims
    *(int4*)(&tile[row][ch * 8]) =
        *(const int4*)(Vb + ((size_t)bh * T_ + t0 + row) * 64 + ch * 8);
  }
  __syncthreads();
  for (int i = 0; i < 2; ++i) {
    int e = tid + i * 256;           // 0..511
    int d = e >> 3, ch = e & 7;      // dim-row, 8 t's
    union { int4 v; ushort u[8]; } pk;
    for (int u = 0; u < 8; ++u) pk.u[u] = tile[ch * 8 + u][d];
    *(int4*)(Vt + ((size_t)bh * 64 + d) * T_ + t0 + ch * 8) = pk.v;
  }
}

// ---------------- fused causal attention: V direct-from-L2, 4 blocks/CU ----------------
__global__ __launch_bounds__(256, 4) void attn_kernel(
    const ushort* __restrict__ Qaug,  // [BH, T, 128]
    const ushort* __restrict__ Kaug,  // [BH, T, 128]
    const ushort* __restrict__ Vt,    // [BH, 64, T]
    float* __restrict__ score,        // [BH, T, T]
    ushort* __restrict__ ctxb) {      // [B*T, 1024] bf16
  // XCD-aware bijective swizzle: each XCD gets 4 whole bh (K+V = 3 MB, L2-resident)
  int flat = blockIdx.y * 32 + blockIdx.x;
  int wg = (flat & 7) * 128 + (flat >> 3);
  int bh = wg >> 5;
  int qt = 31 - (wg & 31);  // biggest blocks first within chunk
  int tid = threadIdx.x;
  int wave = tid >> 6, lane = tid & 63;
  int l16 = lane & 15, lhi = lane >> 4;
  int qb = wave * 16;
  int e7 = l16 & 7;

  __shared__ alignas(16) ushort Ks[2][8192];  // [key 0..63][128], chunk16-XOR-swizzled
  __shared__ alignas(16) ushort Ps[4096];     // [qrow 0..63][64 keys], wave-private rows

  const ushort* Kbase = Kaug + (size_t)bh * T_ * 128;
  const ushort* Vbase = Vt + (size_t)bh * 64 * T_;

  auto stageK = [&](int kt, int buf) {
    for (int i = 0; i < 4; ++i) {
      int rg = i * 4 + wave;               // 16 regions x 4 keys
      int key = rg * 4 + (lane >> 4);
      const ushort* g = Kbase + ((size_t)(kt * 64 + key)) * 128 + (((lane & 15) ^ (key & 7)) << 3);
      g2l16(g, &Ks[buf][rg * 512]);
    }
  };

  // Q -> registers (A-frag: row=l16, k=ks*32+lhi*8)
  bf16x8 qf[4];
  {
    const ushort* Qg = Qaug + ((size_t)bh * T_ + qt * 64 + qb + l16) * 128;
    for (int ks = 0; ks < 4; ++ks)
      qf[ks] = *(const bf16x8*)(Qg + ks * 32 + lhi * 8);
  }

  // ---- sweep 1: denominators (no-max softmax) ----
  stageK(0, 0);
  float plsum[4] = {0.f, 0.f, 0.f, 0.f};
  for (int kt = 0; kt <= qt; ++kt) {
    int buf = kt & 1;
    __syncthreads();
    if (kt < qt) stageK(kt + 1, buf ^ 1);
    const ushort* Kb = Ks[buf];
    f32x4 s[4] = {};
    for (int ks = 0; ks < 4; ++ks)
      for (int fn = 0; fn < 4; ++fn) {
        bf16x8 bfr = *(const bf16x8*)(Kb + (fn * 16 + l16) * 128 + ((((ks << 2) | lhi) ^ e7) << 3));
        s[fn] = __builtin_amdgcn_mfma_f32_16x16x32_bf16(qf[ks], bfr, s[fn], 0, 0, 0);
      }
    if (kt == qt) {
      for (int fn = 0; fn < 4; ++fn)
        for (int r = 0; r < 4; ++r)
          if (fn * 16 + l16 > qb + lhi * 4 + r) s[fn][r] = -1e30f;
    }
    for (int r = 0; r < 4; ++r)
      plsum[r] += __expf(s[0][r]) + __expf(s[1][r]) + __expf(s[2][r]) + __expf(s[3][r]);
  }
  float invl[4];
  for (int r = 0; r < 4; ++r) {
    float v = plsum[r];
    for (int dd = 1; dd < 16; dd <<= 1) v += __shfl_xor(v, dd);
    invl[r] = 1.f / v;
  }

  // ---- sweep 2: P, score write, PV (V direct from L2) ----
  __syncthreads();
  stageK(0, 0);
  f32x4 cacc[4] = {};
  float* srow = score + ((size_t)bh * T_ + (size_t)qt * 64) * T_;

  for (int kt = 0; kt <= qt; ++kt) {
    int buf = kt & 1;
    __syncthreads();
    if (kt < qt) stageK(kt + 1, buf ^ 1);
    const ushort* Kb = Ks[buf];
    f32x4 s[4] = {};
    for (int ks = 0; ks < 4; ++ks)
      for (int fn = 0; fn < 4; ++fn) {
        bf16x8 bfr = *(const bf16x8*)(Kb + (fn * 16 + l16) * 128 + ((((ks << 2) | lhi) ^ e7) << 3));
        s[fn] = __builtin_amdgcn_mfma_f32_16x16x32_bf16(qf[ks], bfr, s[fn], 0, 0, 0);
      }
    if (kt == qt) {
      for (int fn = 0; fn < 4; ++fn)
        for (int r = 0; r < 4; ++r)
          if (fn * 16 + l16 > qb + lhi * 4 + r) s[fn][r] = -1e30f;
    }
    for (int fn = 0; fn < 4; ++fn)
      for (int r = 0; r < 4; ++r) {
        int row_loc = qb + lhi * 4 + r;
        float p = __expf(s[fn][r]) * invl[r];
        srow[(size_t)row_loc * T_ + kt * 64 + fn * 16 + l16] = p;
        Ps[row_loc * 64 + (((fn * 2 + (l16 >> 3)) ^ (row_loc & 7)) << 3) + e7] = f2bf(p);
      }
    // P is wave-private (each wave reads only its own 16 rows): wave-local wait suffices
    asm volatile("s_waitcnt lgkmcnt(0)" ::: "memory");
    __builtin_amdgcn_sched_barrier(0);
    for (int ks = 0; ks < 2; ++ks) {
      bf16x8 pa = *(const bf16x8*)(Ps + (qb + l16) * 64 + ((((ks << 2) | lhi) ^ e7) << 3));
      for (int fn = 0; fn < 4; ++fn) {
        bf16x8 vb = *(const bf16x8*)(Vbase + (size_t)(fn * 16 + l16) * T_ + kt * 64 + ks * 32 + lhi * 8);
        cacc[fn] = __builtin_amdgcn_mfma_f32_16x16x32_bf16(pa, vb, cacc[fn], 0, 0, 0);
      }
    }
  }

  // zero-fill upper-triangle tiles of score
  {
    int row = tid >> 2, c16 = (tid & 3) * 16;
    f32x4 z = {0.f, 0.f, 0.f, 0.f};
    for (int kt = qt + 1; kt < 32; ++kt) {
      f32x4* dst = (f32x4*)(srow + (size_t)row * T_ + kt * 64 + c16);
      for (int u = 0; u < 4; ++u) dst[u] = z;
    }
  }

  // write ctx (bf16) into [B*T, 1024]
  int b = bh >> 4, h = bh & 15;
  for (int fn = 0; fn < 4; ++fn)
    for (int r = 0; r < 4; ++r) {
      int t = qt * 64 + qb + lhi * 4 + r;
      int col = h * 64 + fn * 16 + l16;
      ctxb[((size_t)(b * T_ + t)) * 1024 + col] = f2bf(cacc[fn][r]);
    }
}

extern "C" void kernel_launch(void* const* d_in, const int* in_sizes, int n_in,
                              void* d_out, int out_size, void* d_ws, size_t ws_size,
                              hipStream_t stream) {
  const float* x    = (const float*)d_in[0];
  const float* Wqkv = (const float*)d_in[2];
  const float* Wout = (const float*)d_in[3];
  const float* bout = (const float*)d_in[4];

  char* ws = (char*)d_ws;
  ushort* xb    = (ushort*)(ws + 0);           //  8 MB
  ushort* wqkvT = (ushort*)(ws + 8388608);     //  6 MB
  ushort* woutT = (ushort*)(ws + 14680064);    //  2 MB
  float*  qkv   = (float*) (ws + 16777216);    // 48 MB (dead after augment)
  ushort* Qaug  = (ushort*)(ws + 67108864);    // 16 MB
  ushort* Kaug  = (ushort*)(ws + 83886080);    // 16 MB
  ushort* Vb    = (ushort*)(ws + 100663296);   //  8 MB
  ushort* ctxb  = (ushort*)(ws + 109051904);   //  8 MB
  ushort* Vt    = (ushort*)(ws + 16777216);    //  8 MB, overlaps dead qkv

  float* out   = (float*)d_out;
  float* score = out + (size_t)4194304;  // B*T*D floats, then [B,H,T,T]

  cvt_kernel<<<4096, 256, 0, stream>>>(x, xb);
  dim3 tb(32, 8);
  transpose_cvt<<<dim3(3072 / 32, 1024 / 32), tb, 0, stream>>>(Wqkv, wqkvT, 1024, 3072);
  transpose_cvt<<<dim3(1024 / 32, 1024 / 32), tb, 0, stream>>>(Wout, woutT, 1024, 1024);
  gemm_bf16<<<dim3(24, 32), 256, 0, stream>>>(xb, wqkvT, qkv, nullptr, 4096, 3072, 1024);
  augment_kernel<<<4096, 256, 0, stream>>>(qkv, Qaug, Kaug, Vb);
  transpose_v<<<dim3(32, 32), 256, 0, stream>>>(Vb, Vt);
  attn_kernel<<<dim3(32, 32), 256, 0, stream>>>(Qaug, Kaug, Vt, score, ctxb);
  gemm_bf16<<<dim3(8, 32), 256, 0, stream>>>(ctxb, woutT, out, bout, 4096, 1024, 1024);
}

// Round 11
// 316.283 us; speedup vs baseline: 1.2608x; 1.2608x over previous
//
#include <hip/hip_runtime.h>

typedef __bf16 bf16x8 __attribute__((ext_vector_type(8)));
typedef float f32x4 __attribute__((ext_vector_type(4)));

#define B_ 2
#define T_ 2048
#define D_ 1024
#define H_ 16

__device__ __forceinline__ ushort f2bf(float f) {
  union { float f; unsigned u; } v; v.f = f;
  unsigned u = v.u;
  return (ushort)((u + 0x7FFFu + ((u >> 16) & 1u)) >> 16);
}

// async global->LDS, 16B per lane; LDS dest is wave-uniform base + lane*16
__device__ __forceinline__ void g2l16(const void* g, void* l) {
  __builtin_amdgcn_global_load_lds(
      (const __attribute__((address_space(1))) unsigned int*)g,
      (__attribute__((address_space(3))) unsigned int*)l, 16, 0, 0);
}

// ---------------- cast x -> bf16 ----------------
__global__ __launch_bounds__(256) void cvt_kernel(const float* __restrict__ in,
                                                  ushort* __restrict__ out) {
  int i = (blockIdx.x * 256 + threadIdx.x) * 4;
  float4 v = *(const float4*)(in + i);
  ushort4 o;
  o.x = f2bf(v.x); o.y = f2bf(v.y); o.z = f2bf(v.z); o.w = f2bf(v.w);
  *(ushort4*)(out + i) = o;
}

// ---------------- transpose + cast: in[R][C] f32 -> out[C][R] bf16 ----------------
__global__ void transpose_cvt(const float* __restrict__ in, ushort* __restrict__ out,
                              int R, int C) {
  __shared__ float tile[32][33];
  int bx = blockIdx.x * 32, by = blockIdx.y * 32;
  int tx = threadIdx.x, ty = threadIdx.y;  // block (32,8)
  for (int i = 0; i < 32; i += 8)
    tile[ty + i][tx] = in[(size_t)(by + ty + i) * C + (bx + tx)];
  __syncthreads();
  for (int i = 0; i < 32; i += 8)
    out[(size_t)(bx + ty + i) * R + (by + tx)] = f2bf(tile[tx][ty + i]);
}

// ---------------- bf16 GEMM (m97-style): C[M,N] = A[M,K] * BT[N,K]^T (+bias) ----------------
__global__ __launch_bounds__(256) void gemm_bf16(
    const ushort* __restrict__ A, const ushort* __restrict__ BT,
    float* __restrict__ C, const float* __restrict__ bias,
    int M, int N, int K) {
  __shared__ alignas(16) ushort As[2][4096];  // 128 rows x 32 cols
  __shared__ alignas(16) ushort Bs[2][4096];
  int tid = threadIdx.x;
  int wave = tid >> 6, lane = tid & 63;
  int l16 = lane & 15, lhi = lane >> 4;
  int m0 = blockIdx.y * 128, n0 = blockIdx.x * 128;
  int wr = (wave >> 1) * 64, wc = (wave & 1) * 64;
  int srow = lane >> 2, sch = lane & 3;  // staging: 4 lanes per 64B row

  f32x4 acc[4][4] = {};

  auto stage = [&](int kk, int buf) {
    for (int i = 0; i < 2; ++i) {
      int rg = i * 4 + wave;  // 0..7, 16 rows each
      const ushort* ga = A + (size_t)(m0 + rg * 16 + srow) * K + kk + sch * 8;
      const ushort* gb = BT + (size_t)(n0 + rg * 16 + srow) * K + kk + sch * 8;
      g2l16(ga, &As[buf][rg * 512]);
      g2l16(gb, &Bs[buf][rg * 512]);
    }
  };

  stage(0, 0);
  int buf = 0;
  for (int kk = 0; kk < K; kk += 32) {
    __syncthreads();
    if (kk + 32 < K) stage(kk + 32, buf ^ 1);
    const ushort* Asb = As[buf];
    const ushort* Bsb = Bs[buf];
    bf16x8 af[4], bfr[4];
    for (int f = 0; f < 4; ++f)
      af[f] = *(const bf16x8*)(Asb + (wr + f * 16 + l16) * 32 + lhi * 8);
    for (int f = 0; f < 4; ++f)
      bfr[f] = *(const bf16x8*)(Bsb + (wc + f * 16 + l16) * 32 + lhi * 8);
    for (int fm = 0; fm < 4; ++fm)
      for (int fn = 0; fn < 4; ++fn)
        acc[fm][fn] = __builtin_amdgcn_mfma_f32_16x16x32_bf16(af[fm], bfr[fn], acc[fm][fn], 0, 0, 0);
    buf ^= 1;
  }
  for (int fm = 0; fm < 4; ++fm)
    for (int fn = 0; fn < 4; ++fn)
      for (int r = 0; r < 4; ++r) {
        int row = m0 + wr + fm * 16 + lhi * 4 + r;
        int col = n0 + wc + fn * 16 + l16;
        float v = acc[fm][fn][r];
        if (bias) v += bias[col];
        C[(size_t)row * N + col] = v;
      }
}

// ---------------- build Qaug/Kaug/V from qkv ----------------
__global__ __launch_bounds__(256) void augment_kernel(
    const float* __restrict__ qkv,  // [B*T, 3072]
    ushort* __restrict__ Qaug, ushort* __restrict__ Kaug, ushort* __restrict__ Vb) {
  int row = blockIdx.x;  // b*T + t
  int b = row >> 11;
  int t = row & 2047;
  int tid = threadIdx.x;
  const float* src = qkv + (size_t)row * 3072;
  for (int i = 0; i < 4; ++i) {
    int idx = tid + i * 256;  // 0..1023
    int h = idx >> 6, d = idx & 63;
    size_t obase = ((size_t)(b * H_ + h) * T_ + t);
    float q = src[idx];
    float k = src[1024 + idx];
    float v = src[2048 + idx];
    Qaug[obase * 128 + d] = f2bf(q * 0.125f);
    Kaug[obase * 128 + d] = f2bf(k);
    Vb[obase * 64 + d] = f2bf(v);
  }
  for (int i = 0; i < 2; ++i) {
    int idx = tid + i * 256;  // 0..511
    int h = idx >> 5, mm = idx & 31;
    int gdim = h * 64 + 2 * mm;
    float w = __expf(-9.2103403719761836f * (float)gdim * (1.0f / 1024.0f));
    float ang = w * (float)t;
    float si, co;
    __sincosf(ang, &si, &co);
    float qs = src[h * 64 + 2 * mm], qc = src[h * 64 + 2 * mm + 1];
    size_t obase = ((size_t)(b * H_ + h) * T_ + t);
    Qaug[obase * 128 + 64 + 2 * mm]     = f2bf((qs * si + qc * co) * 0.125f);
    Qaug[obase * 128 + 64 + 2 * mm + 1] = f2bf((qc * si - qs * co) * 0.125f);
    Kaug[obase * 128 + 64 + 2 * mm]     = f2bf(co);
    Kaug[obase * 128 + 64 + 2 * mm + 1] = f2bf(si);
  }
}

// ---------------- transpose V: [BH, T, 64] -> [BH, 64, T] ----------------
__global__ __launch_bounds__(256) void transpose_v(const ushort* __restrict__ Vb,
                                                   ushort* __restrict__ Vt) {
  __shared__ ushort tile[64][72];
  int bh = blockIdx.y, t0 = blockIdx.x * 64;
  int tid = threadIdx.x;
  for (int i = 0; i < 2; ++i) {
    int e = tid + i * 256;           // 0..511
    int row = e >> 3, ch = e & 7;    // t-row, 8 dims
    *(int4*)(&tile[row][ch * 8]) =
        *(const int4*)(Vb + ((size_t)bh * T_ + t0 + row) * 64 + ch * 8);
  }
  __syncthreads();
  for (int i = 0; i < 2; ++i) {
    int e = tid + i * 256;           // 0..511
    int d = e >> 3, ch = e & 7;      // dim-row, 8 t's
    union { int4 v; ushort u[8]; } pk;
    for (int u = 0; u < 8; ++u) pk.u[u] = tile[ch * 8 + u][d];
    *(int4*)(Vt + ((size_t)bh * 64 + d) * T_ + t0 + ch * 8) = pk.v;
  }
}

// ---------------- fused causal attention: counted-vmcnt barriers (T4) ----------------
__global__ __launch_bounds__(256) void attn_kernel(
    const ushort* __restrict__ Qaug,  // [BH, T, 128]
    const ushort* __restrict__ Kaug,  // [BH, T, 128]
    const ushort* __restrict__ Vt,    // [BH, 64, T]
    float* __restrict__ score,        // [BH, T, T]
    ushort* __restrict__ ctxb) {      // [B*T, 1024] bf16
  // XCD-aware bijective swizzle: each XCD gets 4 whole bh (K+V = 3 MB, L2-resident)
  int flat = blockIdx.y * 32 + blockIdx.x;
  int wg = (flat & 7) * 128 + (flat >> 3);
  int bh = wg >> 5;
  int qt = 31 - (wg & 31);  // biggest blocks first within chunk
  int tid = threadIdx.x;
  int wave = tid >> 6, lane = tid & 63;
  int l16 = lane & 15, lhi = lane >> 4;
  int qb = wave * 16;
  int e7 = l16 & 7;

  __shared__ alignas(16) ushort Ks[2][8192];  // [key 0..63][128], chunk16-XOR-swizzled
  __shared__ alignas(16) ushort Vs[2][4096];  // [dim 0..63][64 keys], chunk-XOR-swizzled
  __shared__ alignas(16) ushort Ps[4096];     // [qrow][64 keys], wave-private rows

  const ushort* Kbase = Kaug + (size_t)bh * T_ * 128;
  const ushort* Vbase = Vt + (size_t)bh * 64 * T_;

  auto stageK = [&](int kt, int buf) {
    for (int i = 0; i < 4; ++i) {
      int rg = i * 4 + wave;               // 16 regions x 4 keys
      int key = rg * 4 + (lane >> 4);
      const ushort* g = Kbase + ((size_t)(kt * 64 + key)) * 128 + (((lane & 15) ^ (key & 7)) << 3);
      g2l16(g, &Ks[buf][rg * 512]);
    }
  };
  auto stageV = [&](int kt, int buf) {
    for (int i = 0; i < 2; ++i) {
      int rg = i * 4 + wave;               // 8 regions x 8 dims
      int dim = rg * 8 + (lane >> 3);
      const ushort* g = Vbase + (size_t)dim * T_ + kt * 64 + (((lane & 7) ^ (dim & 7)) << 3);
      g2l16(g, &Vs[buf][rg * 512]);
    }
  };

  // Q -> registers (A-frag: row=l16, k=ks*32+lhi*8)
  bf16x8 qf[4];
  {
    const ushort* Qg = Qaug + ((size_t)bh * T_ + qt * 64 + qb + l16) * 128;
    for (int ks = 0; ks < 4; ++ks)
      qf[ks] = *(const bf16x8*)(Qg + ks * 32 + lhi * 8);
  }

  // ---- sweep 1: denominators (no-max softmax) ----
  stageK(0, 0);
  asm volatile("s_waitcnt vmcnt(0)" ::: "memory");
  __builtin_amdgcn_s_barrier();
  float plsum[4] = {0.f, 0.f, 0.f, 0.f};
  for (int kt = 0; kt <= qt; ++kt) {
    int buf = kt & 1;
    if (kt < qt) stageK(kt + 1, buf ^ 1);
    __builtin_amdgcn_sched_barrier(0);
    const ushort* Kb = Ks[buf];
    f32x4 s[4] = {};
    for (int ks = 0; ks < 4; ++ks)
      for (int fn = 0; fn < 4; ++fn) {
        bf16x8 bfr = *(const bf16x8*)(Kb + (fn * 16 + l16) * 128 + ((((ks << 2) | lhi) ^ e7) << 3));
        s[fn] = __builtin_amdgcn_mfma_f32_16x16x32_bf16(qf[ks], bfr, s[fn], 0, 0, 0);
      }
    if (kt == qt) {
      for (int fn = 0; fn < 4; ++fn)
        for (int r = 0; r < 4; ++r)
          if (fn * 16 + l16 > qb + lhi * 4 + r) s[fn][r] = -1e30f;
    }
    for (int r = 0; r < 4; ++r)
      plsum[r] += __expf(s[0][r]) + __expf(s[1][r]) + __expf(s[2][r]) + __expf(s[3][r]);
    if (kt < qt) {
      asm volatile("s_waitcnt vmcnt(0)" ::: "memory");
      __builtin_amdgcn_s_barrier();
    }
  }
  float invl[4];
  for (int r = 0; r < 4; ++r) {
    float v = plsum[r];
    for (int dd = 1; dd < 16; dd <<= 1) v += __shfl_xor(v, dd);
    invl[r] = 1.f / v;
  }

  // ---- sweep 2: P, score write, PV; stores stay in flight across barriers ----
  __builtin_amdgcn_s_barrier();  // all waves done reading sweep-1 buffers
  stageK(0, 0);
  stageV(0, 0);
  asm volatile("s_waitcnt vmcnt(0)" ::: "memory");
  __builtin_amdgcn_s_barrier();
  f32x4 cacc[4] = {};
  float* srow = score + ((size_t)bh * T_ + (size_t)qt * 64) * T_;

  for (int kt = 0; kt <= qt; ++kt) {
    int buf = kt & 1;
    if (kt < qt) { stageK(kt + 1, buf ^ 1); stageV(kt + 1, buf ^ 1); }
    __builtin_amdgcn_sched_barrier(0);
    const ushort* Kb = Ks[buf];
    f32x4 s[4] = {};
    for (int ks = 0; ks < 4; ++ks)
      for (int fn = 0; fn < 4; ++fn) {
        bf16x8 bfr = *(const bf16x8*)(Kb + (fn * 16 + l16) * 128 + ((((ks << 2) | lhi) ^ e7) << 3));
        s[fn] = __builtin_amdgcn_mfma_f32_16x16x32_bf16(qf[ks], bfr, s[fn], 0, 0, 0);
      }
    if (kt == qt) {
      for (int fn = 0; fn < 4; ++fn)
        for (int r = 0; r < 4; ++r)
          if (fn * 16 + l16 > qb + lhi * 4 + r) s[fn][r] = -1e30f;
    }
    for (int fn = 0; fn < 4; ++fn)
      for (int r = 0; r < 4; ++r) {
        int row_loc = qb + lhi * 4 + r;
        float p = __expf(s[fn][r]) * invl[r];
        srow[(size_t)row_loc * T_ + kt * 64 + fn * 16 + l16] = p;
        Ps[row_loc * 64 + (((fn * 2 + (l16 >> 3)) ^ (row_loc & 7)) << 3) + e7] = f2bf(p);
      }
    // P is wave-private (each wave reads only its own 16 rows): wave-local wait suffices
    asm volatile("s_waitcnt lgkmcnt(0)" ::: "memory");
    __builtin_amdgcn_sched_barrier(0);
    const ushort* Vb2 = Vs[buf];
    for (int ks = 0; ks < 2; ++ks) {
      bf16x8 pa = *(const bf16x8*)(Ps + (qb + l16) * 64 + ((((ks << 2) | lhi) ^ e7) << 3));
      for (int fn = 0; fn < 4; ++fn) {
        bf16x8 vb = *(const bf16x8*)(Vb2 + (fn * 16 + l16) * 64 + ((((ks << 2) | lhi) ^ e7) << 3));
        cacc[fn] = __builtin_amdgcn_mfma_f32_16x16x32_bf16(pa, vb, cacc[fn], 0, 0, 0);
      }
    }
    if (kt < qt) {
      // drain the 6 staging loads (older); leave the 16 score stores (youngest) in flight
      asm volatile("s_waitcnt vmcnt(16)" ::: "memory");
      __builtin_amdgcn_s_barrier();
    }
  }

  // zero-fill upper-triangle tiles of score
  {
    int row = tid >> 2, c16 = (tid & 3) * 16;
    f32x4 z = {0.f, 0.f, 0.f, 0.f};
    for (int kt = qt + 1; kt < 32; ++kt) {
      f32x4* dst = (f32x4*)(srow + (size_t)row * T_ + kt * 64 + c16);
      for (int u = 0; u < 4; ++u) dst[u] = z;
    }
  }

  // write ctx (bf16) into [B*T, 1024]
  int b = bh >> 4, h = bh & 15;
  for (int fn = 0; fn < 4; ++fn)
    for (int r = 0; r < 4; ++r) {
      int t = qt * 64 + qb + lhi * 4 + r;
      int col = h * 64 + fn * 16 + l16;
      ctxb[((size_t)(b * T_ + t)) * 1024 + col] = f2bf(cacc[fn][r]);
    }
}

extern "C" void kernel_launch(void* const* d_in, const int* in_sizes, int n_in,
                              void* d_out, int out_size, void* d_ws, size_t ws_size,
                              hipStream_t stream) {
  const float* x    = (const float*)d_in[0];
  const float* Wqkv = (const float*)d_in[2];
  const float* Wout = (const float*)d_in[3];
  const float* bout = (const float*)d_in[4];

  char* ws = (char*)d_ws;
  ushort* xb    = (ushort*)(ws + 0);           //  8 MB
  ushort* wqkvT = (ushort*)(ws + 8388608);     //  6 MB
  ushort* woutT = (ushort*)(ws + 14680064);    //  2 MB
  float*  qkv   = (float*) (ws + 16777216);    // 48 MB (dead after augment)
  ushort* Qaug  = (ushort*)(ws + 67108864);    // 16 MB
  ushort* Kaug  = (ushort*)(ws + 83886080);    // 16 MB
  ushort* Vb    = (ushort*)(ws + 100663296);   //  8 MB
  ushort* ctxb  = (ushort*)(ws + 109051904);   //  8 MB
  ushort* Vt    = (ushort*)(ws + 16777216);    //  8 MB, overlaps dead qkv

  float* out   = (float*)d_out;
  float* score = out + (size_t)4194304;  // B*T*D floats, then [B,H,T,T]

  cvt_kernel<<<4096, 256, 0, stream>>>(x, xb);
  dim3 tb(32, 8);
  transpose_cvt<<<dim3(3072 / 32, 1024 / 32), tb, 0, stream>>>(Wqkv, wqkvT, 1024, 3072);
  transpose_cvt<<<dim3(1024 / 32, 1024 / 32), tb, 0, stream>>>(Wout, woutT, 1024, 1024);
  gemm_bf16<<<dim3(24, 32), 256, 0, stream>>>(xb, wqkvT, qkv, nullptr, 4096, 3072, 1024);
  augment_kernel<<<4096, 256, 0, stream>>>(qkv, Qaug, Kaug, Vb);
  transpose_v<<<dim3(32, 32), 256, 0, stream>>>(Vb, Vt);
  attn_kernel<<<dim3(32, 32), 256, 0, stream>>>(Qaug, Kaug, Vt, score, ctxb);
  gemm_bf16<<<dim3(8, 32), 256, 0, stream>>>(ctxb, woutT, out, bout, 4096, 1024, 1024);
}